// Round 8
// baseline (221.653 us; speedup 1.0000x reference)
//
#include <hip/hip_runtime.h>

#define Bsz   32
#define Hh    8
#define Ww    128
#define Cc    512
#define NHEAD 8
#define HD    64
#define NN    1024
#define SCALE 0.125f
#define ROWS  1536

typedef _Float16 f16x8 __attribute__((ext_vector_type(8)));
typedef float    f32x4 __attribute__((ext_vector_type(4)));

// ---------------------------------------------------------------------------
// async global->LDS, 16B per lane (linear dest = wave base + lane*16)
// ---------------------------------------------------------------------------
__device__ __forceinline__ void gload16(const _Float16* g, _Float16* l) {
#if __has_builtin(__builtin_amdgcn_global_load_lds)
  __builtin_amdgcn_global_load_lds(
      (const __attribute__((address_space(1))) unsigned int*)g,
      (__attribute__((address_space(3))) unsigned int*)l, 16, 0, 0);
#else
  *(uint4*)l = *(const uint4*)g;
#endif
}

// ---------------------------------------------------------------------------
// converts
// ---------------------------------------------------------------------------
__global__ __launch_bounds__(256) void cvt_f32_f16(
    const float* __restrict__ in, _Float16* __restrict__ out, int n4) {
  const int i = blockIdx.x * 256 + threadIdx.x;
  if (i < n4) {
    const float4 v = *reinterpret_cast<const float4*>(&in[(size_t)i * 4]);
    _Float16 h[4] = {(_Float16)v.x, (_Float16)v.y, (_Float16)v.z, (_Float16)v.w};
    *reinterpret_cast<uint2*>(&out[(size_t)i * 4]) = *reinterpret_cast<uint2*>(h);
  }
}

// out[n*K + k] = in[k*Nn + n]  (f32 -> f16 transpose)
__global__ __launch_bounds__(256) void tcvt(
    const float* __restrict__ in, _Float16* __restrict__ out, int Nn, int K) {
  const int id = blockIdx.x * 256 + threadIdx.x;
  if (id < Nn * K) {
    const int n = id / K, k = id - n * K;
    out[id] = (_Float16)in[(size_t)k * Nn + n];
  }
}

// ---------------------------------------------------------------------------
// MFMA GEMM: C[M,Nn] = A[M,K](f16) * BT[Nn,K]^T(f16)  (+bias), 128x128 tile,
// BK=32, 4 waves, 4x4 fragments of mfma_f32_16x16x32_f16 per wave.
// ---------------------------------------------------------------------------
template<bool OUT_F16, bool HAS_BIAS>
__global__ __launch_bounds__(256, 2) void gemm_mfma(
    const _Float16* __restrict__ A,
    const _Float16* __restrict__ BT,
    const float* __restrict__ bias,
    void* __restrict__ Cout,
    int Nn, int K)
{
  __shared__ _Float16 As[128 * 32];
  __shared__ _Float16 Bs[128 * 32];

  const int t  = threadIdx.x;
  const int bn = blockIdx.x * 128;
  const int bm = blockIdx.y * 128;
  const int l  = t & 63, wv = t >> 6;
  const int wr = wv >> 1, wc = wv & 1;

  f32x4 acc[4][4] = {};

  const int arow = t >> 2;            // 0..63
  const int ac   = (t & 3) * 8;       // k chunk start (halfs)

  for (int k0 = 0; k0 < K; k0 += 32) {
    __syncthreads();
    gload16(A  + (size_t)(bm + arow)      * K + k0 + ac, &As[t * 8]);
    gload16(A  + (size_t)(bm + 64 + arow) * K + k0 + ac, &As[2048 + t * 8]);
    gload16(BT + (size_t)(bn + arow)      * K + k0 + ac, &Bs[t * 8]);
    gload16(BT + (size_t)(bn + 64 + arow) * K + k0 + ac, &Bs[2048 + t * 8]);
    __syncthreads();

    const int rA = l & 15, ks = (l >> 4) * 8;
    f16x8 aF[4], bF[4];
#pragma unroll
    for (int i = 0; i < 4; ++i)
      aF[i] = *(const f16x8*)&As[(wr * 64 + i * 16 + rA) * 32 + ks];
#pragma unroll
    for (int j = 0; j < 4; ++j)
      bF[j] = *(const f16x8*)&Bs[(wc * 64 + j * 16 + rA) * 32 + ks];
#pragma unroll
    for (int i = 0; i < 4; ++i)
#pragma unroll
      for (int j = 0; j < 4; ++j)
        acc[i][j] = __builtin_amdgcn_mfma_f32_16x16x32_f16(aF[i], bF[j], acc[i][j], 0, 0, 0);
  }

  const int lc = l & 15, lr4 = (l >> 4) * 4;
#pragma unroll
  for (int i = 0; i < 4; ++i) {
    const size_t row0 = (size_t)(bm + wr * 64 + i * 16 + lr4);
#pragma unroll
    for (int j = 0; j < 4; ++j) {
      const int col = bn + wc * 64 + j * 16 + lc;
      const float bv = HAS_BIAS ? bias[col] : 0.f;
#pragma unroll
      for (int r = 0; r < 4; ++r) {
        const float v = acc[i][j][r] + bv;
        if (OUT_F16)
          ((_Float16*)Cout)[(row0 + r) * Nn + col] = (_Float16)v;
        else
          ((float*)Cout)[(row0 + r) * Nn + col] = v;
      }
    }
  }
}

// ---------------------------------------------------------------------------
// MFMA local attention, h-paired + XCD-chunked, LDS-minimal (25.5KB -> 4
// blocks/CU, 32 waves = full occupancy). K is NOT staged in LDS: each K row
// is 16KB and L1-resident after first touch; QK^T loads kF fragments
// directly from global (16B/lane, L1 hits for 7 of 8 waves + both hi).
// V must be transposed -> staged in Vsh [d][132-pad] by threads t<256
// (packed uint2 writes, ~2-way). Per key row kr: syncthreads -> V stage ->
// syncthreads -> per-h: QK^T mfma (kF from global), mask, online softmax
// (16-lane shfl), P->Pbuf (stride-36, conflict-free), PV mfma.
// ---------------------------------------------------------------------------
__global__ __launch_bounds__(512, 4) void local_attn_mfma(
    const _Float16* __restrict__ qkv, _Float16* __restrict__ outh)
{
  const int wg  = blockIdx.x + (Hh / 2) * (blockIdx.y + NHEAD * blockIdx.z);
  const int nid = ((wg & 7) << 7) + (wg >> 3);
  const int hp = nid & 3, head = (nid >> 2) & 7, b = nid >> 5;
  const int h0 = hp * 2;

  const int t = threadIdx.x;
  const int l = t & 63;
  const int g = l >> 4, c = l & 15;
  const int w0 = (t >> 6) * 16;               // wave's query-col tile base
  const int kb = min(max(w0 - 8, 0), 96);     // 8-aligned key tile base

  __shared__ _Float16 Vsh[64 * 132];          // [d][132-pad cols]
  __shared__ _Float16 Pbuf[8][576];           // [wave][q*36 + z]

  const _Float16* qb = qkv + (size_t)b * NN * ROWS;

  // ---- Q fragments for both h rows (A-frag: row=c, k = s*32 + g*8..+7) ----
  f16x8 qF[2][2];
#pragma unroll
  for (int hi = 0; hi < 2; ++hi) {
    const _Float16* Qg = qb + (size_t)((h0 + hi) * Ww + w0 + c) * ROWS + head * HD;
    qF[hi][0] = *(const f16x8*)&Qg[g * 8];
    qF[hi][1] = *(const f16x8*)&Qg[32 + g * 8];
  }

  // h-independent column masks (per accumulator row r)
  bool cm0[4], cm1[4];
#pragma unroll
  for (int r = 0; r < 4; ++r) {
    const int w = w0 + g * 4 + r;
    cm0[r] = (kb + c      >= w - 5) && (kb + c      <= w + 5);
    cm1[r] = (kb + 16 + c >= w - 5) && (kb + 16 + c <= w + 5);
  }

  const int r0 = max(0, h0 - 3), r1 = min(Hh - 1, h0 + 4);
  float m_run[2][4], s_run[2][4];
  f32x4 accO[2][4] = {};
#pragma unroll
  for (int hi = 0; hi < 2; ++hi)
#pragma unroll
    for (int r = 0; r < 4; ++r) { m_run[hi][r] = -1e30f; s_run[hi][r] = 0.f; }

  // V staging coords (threads t<256: 4 cols x 8 d each)
  const int dd = t & 7, cg = (t & 255) >> 3;

  for (int kr = r0; kr <= r1; ++kr) {
    __syncthreads();                          // prev PV reads of Vsh done
    if (t < 256) {
      f16x8 vr[4];
      const _Float16* Vg = qb + (size_t)(kr * Ww + cg * 4) * ROWS + 2 * Cc + head * HD + dd * 8;
#pragma unroll
      for (int i = 0; i < 4; ++i)
        vr[i] = *(const f16x8*)&Vg[(size_t)i * ROWS];
#pragma unroll
      for (int e = 0; e < 8; ++e) {
        union { _Float16 hh[4]; uint2 u; } pk;
        pk.hh[0] = vr[0][e]; pk.hh[1] = vr[1][e];
        pk.hh[2] = vr[2][e]; pk.hh[3] = vr[3][e];
        *(uint2*)&Vsh[(dd * 8 + e) * 132 + cg * 4] = pk.u;
      }
    }
    __syncthreads();                          // Vsh published

    const _Float16* Kg = qb + (size_t)(kr * Ww) * ROWS + Cc + head * HD;

#pragma unroll
    for (int hi = 0; hi < 2; ++hi) {
      const int hq = h0 + hi;
      if (kr < hq - 3 || kr > hq + 3) continue;

      // ---- QK^T: S[q=g*4+r][kcol = kb+16tt+c]; kF direct from global/L1 ----
      f32x4 accS[2] = {};
#pragma unroll
      for (int tt = 0; tt < 2; ++tt) {
        const int col = kb + 16 * tt + c;
#pragma unroll
        for (int s = 0; s < 2; ++s) {
          const f16x8 kF = *(const f16x8*)&Kg[(size_t)col * ROWS + (s * 4 + g) * 8];
          accS[tt] = __builtin_amdgcn_mfma_f32_16x16x32_f16(qF[hi][s], kF, accS[tt], 0, 0, 0);
        }
      }

      // ---- mask + online softmax (16-lane-group reduce) ----
      float alpha[4];
#pragma unroll
      for (int r = 0; r < 4; ++r) {
        float s0 = cm0[r] ? accS[0][r] * SCALE : -1e30f;
        float s1 = cm1[r] ? accS[1][r] * SCALE : -1e30f;
        float mx = fmaxf(s0, s1);
#pragma unroll
        for (int msk = 1; msk < 16; msk <<= 1)
          mx = fmaxf(mx, __shfl_xor(mx, msk));
        const float mnew = fmaxf(m_run[hi][r], mx);
        const float p0 = __expf(s0 - mnew);
        const float p1 = __expf(s1 - mnew);
        alpha[r] = __expf(m_run[hi][r] - mnew);
        float ps = p0 + p1;
#pragma unroll
        for (int msk = 1; msk < 16; msk <<= 1)
          ps += __shfl_xor(ps, msk);
        s_run[hi][r] = s_run[hi][r] * alpha[r] + ps;
        m_run[hi][r] = mnew;
        const int q = g * 4 + r;
        Pbuf[t >> 6][q * 36 + c]      = (_Float16)p0;  // bank = 8g + c/2 + const
        Pbuf[t >> 6][q * 36 + 16 + c] = (_Float16)p1;
      }

      // wave-local: drain P writes before re-reading as A-fragment
      asm volatile("s_waitcnt lgkmcnt(0)" ::: "memory");

      // ---- PV: O[q][d=16jj+c] += P(16x32) * V(32x64-window) ----
      union { f16x8 v; uint2 u2[2]; } pF;
      {
        const _Float16* pp = &Pbuf[t >> 6][c * 36 + g * 8];
        pF.u2[0] = *(const uint2*)pp;
        pF.u2[1] = *(const uint2*)(pp + 4);
      }
#pragma unroll
      for (int jj = 0; jj < 4; ++jj)
#pragma unroll
        for (int r = 0; r < 4; ++r) accO[hi][jj][r] *= alpha[r];
#pragma unroll
      for (int jj = 0; jj < 4; ++jj) {
        union { f16x8 v; uint2 u2[2]; } vF;
        const _Float16* vp = &Vsh[(16 * jj + c) * 132 + kb + g * 8];
        vF.u2[0] = *(const uint2*)vp;
        vF.u2[1] = *(const uint2*)(vp + 4);
        accO[hi][jj] = __builtin_amdgcn_mfma_f32_16x16x32_f16(pF.v, vF.v, accO[hi][jj], 0, 0, 0);
      }
    }
  }

  // ---- epilogue: normalize, store f16 for both h rows ----
#pragma unroll
  for (int hi = 0; hi < 2; ++hi) {
    _Float16* ob = outh + ((size_t)b * NN + (h0 + hi) * Ww + w0) * Cc + head * HD;
#pragma unroll
    for (int r = 0; r < 4; ++r) {
      const float inv = 1.f / s_run[hi][r];
      const int q = g * 4 + r;
#pragma unroll
      for (int jj = 0; jj < 4; ++jj)
        ob[(size_t)q * Cc + 16 * jj + c] = (_Float16)(accO[hi][jj][r] * inv);
    }
  }
}

// ---------------------------------------------------------------------------
extern "C" void kernel_launch(void* const* d_in, const int* in_sizes, int n_in,
                              void* d_out, int out_size, void* d_ws, size_t ws_size,
                              hipStream_t stream)
{
  const float* x      = (const float*)d_in[0];   // [32,1024,512]
  const float* w_qkv  = (const float*)d_in[1];   // [512,1536]
  const float* w_proj = (const float*)d_in[2];   // [512,512]
  const float* b_proj = (const float*)d_in[3];   // [512]
  float* out = (float*)d_out;

  const int M = Bsz * NN;                        // 32768
  char* ws = (char*)d_ws;
  _Float16* xh    = (_Float16*)ws;                              // 33.55 MB
  _Float16* qkvh  = (_Float16*)(ws + 33554432);                 // 100.66 MB
  _Float16* attnh = (_Float16*)(ws + 33554432 + 100663296);     // 33.55 MB
  _Float16* wqT   = (_Float16*)(ws + 167772160);                // 1.57 MB
  _Float16* wpT   = (_Float16*)(ws + 167772160 + 1572864);      // 0.52 MB

  // converts
  cvt_f32_f16<<<(M * Cc / 4 + 255) / 256, 256, 0, stream>>>(x, xh, M * Cc / 4);
  tcvt<<<(ROWS * Cc + 255) / 256, 256, 0, stream>>>(w_qkv, wqT, ROWS, Cc);
  tcvt<<<(Cc * Cc + 255) / 256, 256, 0, stream>>>(w_proj, wpT, Cc, Cc);

  // qkv = x @ w_qkv   (f16 out)
  gemm_mfma<true, false><<<dim3(ROWS / 128, M / 128), 256, 0, stream>>>(
      xh, wqT, nullptr, qkvh, ROWS, Cc);

  // local attention (MFMA, h-paired, LDS-minimal) -> f16 [32768,512]
  local_attn_mfma<<<dim3(Hh / 2, NHEAD, Bsz), 512, 0, stream>>>(qkvh, attnh);

  // out = attn @ w_proj + bias  (f32 out)
  gemm_mfma<false, true><<<dim3(Cc / 128, M / 128), 256, 0, stream>>>(
      attnh, wpT, b_proj, out, Cc, Cc);
}

// Round 9
// 213.039 us; speedup vs baseline: 1.0404x; 1.0404x over previous
//
#include <hip/hip_runtime.h>

#define Bsz   32
#define Hh    8
#define Ww    128
#define Cc    512
#define NHEAD 8
#define HD    64
#define NN    1024
#define SCALE 0.125f
#define ROWS  1536

typedef _Float16 f16x8 __attribute__((ext_vector_type(8)));
typedef float    f32x4 __attribute__((ext_vector_type(4)));

// ---------------------------------------------------------------------------
// async global->LDS, 16B per lane (linear dest = wave base + lane*16)
// ---------------------------------------------------------------------------
__device__ __forceinline__ void gload16(const _Float16* g, _Float16* l) {
#if __has_builtin(__builtin_amdgcn_global_load_lds)
  __builtin_amdgcn_global_load_lds(
      (const __attribute__((address_space(1))) unsigned int*)g,
      (__attribute__((address_space(3))) unsigned int*)l, 16, 0, 0);
#else
  *(uint4*)l = *(const uint4*)g;
#endif
}

// out[n*K + k] = in[k*Nn + n]  (f32 -> f16 transpose)
__global__ __launch_bounds__(256) void tcvt(
    const float* __restrict__ in, _Float16* __restrict__ out, int Nn, int K) {
  const int id = blockIdx.x * 256 + threadIdx.x;
  if (id < Nn * K) {
    const int n = id / K, k = id - n * K;
    out[id] = (_Float16)in[(size_t)k * Nn + n];
  }
}

// ---------------------------------------------------------------------------
// MFMA GEMM: C[M,Nn] = A[M,K] * BT[Nn,K]^T (f16 MFMA, +bias), 128x128 tile,
// BK=32, 4 waves, 4x4 fragments of mfma_f32_16x16x32_f16 per wave.
// A_F32: A is fp32 in global; staged via reg-convert + ds_write_b128 into the
// same As layout (fuses the x->f16 convert into the GEMM, saving the 201MB
// standalone-convert round trip). Otherwise A is f16 via global_load_lds.
// ---------------------------------------------------------------------------
template<bool A_F32, bool OUT_F16, bool HAS_BIAS>
__global__ __launch_bounds__(256, 2) void gemm_mfma(
    const void* __restrict__ Ap,
    const _Float16* __restrict__ BT,
    const float* __restrict__ bias,
    void* __restrict__ Cout,
    int Nn, int K)
{
  __shared__ _Float16 As[128 * 32];
  __shared__ _Float16 Bs[128 * 32];

  const int t  = threadIdx.x;
  const int bn = blockIdx.x * 128;
  const int bm = blockIdx.y * 128;
  const int l  = t & 63, wv = t >> 6;
  const int wr = wv >> 1, wc = wv & 1;

  f32x4 acc[4][4] = {};

  const int arow = t >> 2;            // 0..63
  const int ac   = (t & 3) * 8;       // k chunk start (halfs)

  for (int k0 = 0; k0 < K; k0 += 32) {
    __syncthreads();
    if constexpr (A_F32) {
      const float* Af = (const float*)Ap;
#pragma unroll
      for (int rr = 0; rr < 2; ++rr) {
        const float* src = &Af[(size_t)(bm + arow + rr * 64) * K + k0 + ac];
        const float4 f0 = *(const float4*)src;
        const float4 f1 = *(const float4*)(src + 4);
        union { _Float16 h[8]; uint4 u; } pk;
        pk.h[0] = (_Float16)f0.x; pk.h[1] = (_Float16)f0.y;
        pk.h[2] = (_Float16)f0.z; pk.h[3] = (_Float16)f0.w;
        pk.h[4] = (_Float16)f1.x; pk.h[5] = (_Float16)f1.y;
        pk.h[6] = (_Float16)f1.z; pk.h[7] = (_Float16)f1.w;
        *(uint4*)&As[(arow + rr * 64) * 32 + ac] = pk.u;
      }
    } else {
      const _Float16* Ah = (const _Float16*)Ap;
      gload16(Ah + (size_t)(bm + arow)      * K + k0 + ac, &As[t * 8]);
      gload16(Ah + (size_t)(bm + 64 + arow) * K + k0 + ac, &As[2048 + t * 8]);
    }
    gload16(BT + (size_t)(bn + arow)      * K + k0 + ac, &Bs[t * 8]);
    gload16(BT + (size_t)(bn + 64 + arow) * K + k0 + ac, &Bs[2048 + t * 8]);
    __syncthreads();

    const int rA = l & 15, ks = (l >> 4) * 8;
    f16x8 aF[4], bF[4];
#pragma unroll
    for (int i = 0; i < 4; ++i)
      aF[i] = *(const f16x8*)&As[(wr * 64 + i * 16 + rA) * 32 + ks];
#pragma unroll
    for (int j = 0; j < 4; ++j)
      bF[j] = *(const f16x8*)&Bs[(wc * 64 + j * 16 + rA) * 32 + ks];
#pragma unroll
    for (int i = 0; i < 4; ++i)
#pragma unroll
      for (int j = 0; j < 4; ++j)
        acc[i][j] = __builtin_amdgcn_mfma_f32_16x16x32_f16(aF[i], bF[j], acc[i][j], 0, 0, 0);
  }

  const int lc = l & 15, lr4 = (l >> 4) * 4;
#pragma unroll
  for (int i = 0; i < 4; ++i) {
    const size_t row0 = (size_t)(bm + wr * 64 + i * 16 + lr4);
#pragma unroll
    for (int j = 0; j < 4; ++j) {
      const int col = bn + wc * 64 + j * 16 + lc;
      const float bv = HAS_BIAS ? bias[col] : 0.f;
#pragma unroll
      for (int r = 0; r < 4; ++r) {
        const float v = acc[i][j][r] + bv;
        if (OUT_F16)
          ((_Float16*)Cout)[(row0 + r) * Nn + col] = (_Float16)v;
        else
          ((float*)Cout)[(row0 + r) * Nn + col] = v;
      }
    }
  }
}

// ---------------------------------------------------------------------------
// MFMA local attention, h-paired + XCD-chunked + SWAPPED-QK softmax.
// QK^T computed as mfma(kF, qF) -- identical operand registers to the
// straight form, but output maps to S[kcol=kb+16tt+4g+r][q=w0+c]: each lane
// owns 8 scores of ONE query -> row softmax is 7 local fmax + 2 shfl (g-xor
// 16/32), 8 exps, + 4 shfl to redistribute alpha to PV's q=4g+r rows.
// (was: 4 sequential per-row reductions x 8 shfl = 32 shuffles per hi,kr).
// Mask folded into an additive bias: s = fma(acc, SCALE, mbias).
// K read direct from global (L1/L2); V transposed into Vsh [d][132-pad];
// P via Pbuf [q*36+kcol] (2x uint2 stores/lane, ~2-way); PV mfma unchanged.
// ---------------------------------------------------------------------------
__global__ __launch_bounds__(512, 4) void local_attn_mfma(
    const _Float16* __restrict__ qkv, _Float16* __restrict__ outh)
{
  const int wg  = blockIdx.x + (Hh / 2) * (blockIdx.y + NHEAD * blockIdx.z);
  const int nid = ((wg & 7) << 7) + (wg >> 3);
  const int hp = nid & 3, head = (nid >> 2) & 7, b = nid >> 5;
  const int h0 = hp * 2;

  const int t = threadIdx.x;
  const int wv = t >> 6, l = t & 63;
  const int g = l >> 4, c = l & 15;
  const int w0 = wv * 16;                     // wave's query-col tile base
  const int kb = min(max(w0 - 8, 0), 96);     // 8-aligned key tile base

  __shared__ _Float16 Vsh[64 * 132];          // [d][132-pad cols]
  __shared__ _Float16 Pbuf[8][576];           // [wave][q*36 + kcol]

  const _Float16* qb = qkv + (size_t)b * NN * ROWS;

  // ---- Q fragments (lane c holds Q[w0+c][k-slice]; used as B-operand) ----
  f16x8 qF[2][2];
#pragma unroll
  for (int hi = 0; hi < 2; ++hi) {
    const _Float16* Qg = qb + (size_t)((h0 + hi) * Ww + w0 + c) * ROWS + head * HD;
    qF[hi][0] = *(const f16x8*)&Qg[g * 8];
    qF[hi][1] = *(const f16x8*)&Qg[32 + g * 8];
  }

  // ---- additive mask bias: kcol = kb+16tt+4g+r vs q = w0+c (h-indep) ----
  float mbias[2][4];
#pragma unroll
  for (int tt = 0; tt < 2; ++tt)
#pragma unroll
    for (int r = 0; r < 4; ++r) {
      const int kcol = kb + 16 * tt + 4 * g + r;
      const int qq   = w0 + c;
      mbias[tt][r] = (kcol >= qq - 5 && kcol <= qq + 5) ? 0.f : -1e30f;
    }

  const int r0 = max(0, h0 - 3), r1 = min(Hh - 1, h0 + 4);
  float m_run[2] = {-1e30f, -1e30f}, s_run[2] = {0.f, 0.f};
  f32x4 accO[2][4] = {};

  // V staging coords (threads t<256: 4 cols x 8 d each)
  const int dd = t & 7, cg = (t & 255) >> 3;

  for (int kr = r0; kr <= r1; ++kr) {
    __syncthreads();                          // prev PV reads of Vsh done
    if (t < 256) {
      f16x8 vr[4];
      const _Float16* Vg = qb + (size_t)(kr * Ww + cg * 4) * ROWS + 2 * Cc + head * HD + dd * 8;
#pragma unroll
      for (int i = 0; i < 4; ++i)
        vr[i] = *(const f16x8*)&Vg[(size_t)i * ROWS];
#pragma unroll
      for (int e = 0; e < 8; ++e) {
        union { _Float16 hh[4]; uint2 u; } pk;
        pk.hh[0] = vr[0][e]; pk.hh[1] = vr[1][e];
        pk.hh[2] = vr[2][e]; pk.hh[3] = vr[3][e];
        *(uint2*)&Vsh[(dd * 8 + e) * 132 + cg * 4] = pk.u;
      }
    }
    __syncthreads();                          // Vsh published

    const _Float16* Kg = qb + (size_t)(kr * Ww) * ROWS + Cc + head * HD;

#pragma unroll
    for (int hi = 0; hi < 2; ++hi) {
      const int hq = h0 + hi;
      if (kr < hq - 3 || kr > hq + 3) continue;

      // ---- swapped QK^T: Ssw[kcol_local=4g+r (+16tt)][q=c] ----
      f32x4 accS[2] = {};
#pragma unroll
      for (int tt = 0; tt < 2; ++tt) {
        const int col = kb + 16 * tt + c;
#pragma unroll
        for (int s = 0; s < 2; ++s) {
          const f16x8 kF = *(const f16x8*)&Kg[(size_t)col * ROWS + (s * 4 + g) * 8];
          accS[tt] = __builtin_amdgcn_mfma_f32_16x16x32_f16(kF, qF[hi][s], accS[tt], 0, 0, 0);
        }
      }

      // ---- lane-local softmax for query q = w0+c ----
      float sc[2][4];
      float smax = -1e30f;
#pragma unroll
      for (int tt = 0; tt < 2; ++tt)
#pragma unroll
        for (int r = 0; r < 4; ++r) {
          sc[tt][r] = __builtin_fmaf(accS[tt][r], SCALE, mbias[tt][r]);
          smax = fmaxf(smax, sc[tt][r]);
        }
      smax = fmaxf(smax, __shfl_xor(smax, 16));
      smax = fmaxf(smax, __shfl_xor(smax, 32));
      const float mnew  = fmaxf(m_run[hi], smax);
      const float alpha = __expf(m_run[hi] - mnew);
      m_run[hi] = mnew;

      float ps = 0.f;
#pragma unroll
      for (int tt = 0; tt < 2; ++tt) {
        float p0 = __expf(sc[tt][0] - mnew), p1 = __expf(sc[tt][1] - mnew);
        float p2 = __expf(sc[tt][2] - mnew), p3 = __expf(sc[tt][3] - mnew);
        ps += (p0 + p1) + (p2 + p3);
        union { _Float16 hh[4]; uint2 u; } pk;
        pk.hh[0] = (_Float16)p0; pk.hh[1] = (_Float16)p1;
        pk.hh[2] = (_Float16)p2; pk.hh[3] = (_Float16)p3;
        *(uint2*)&Pbuf[wv][c * 36 + 16 * tt + 4 * g] = pk.u;
      }
      ps += __shfl_xor(ps, 16);
      ps += __shfl_xor(ps, 32);
      s_run[hi] = s_run[hi] * alpha + ps;

      // redistribute alpha to this lane's accO rows (q = 4g+r)
      float alr[4];
#pragma unroll
      for (int r = 0; r < 4; ++r)
        alr[r] = __shfl(alpha, 4 * g + r, 16);

      // wave-local: drain P writes before re-reading as A-fragment
      asm volatile("s_waitcnt lgkmcnt(0)" ::: "memory");

      // ---- PV: O[q=4g+r][d=16jj+c] += P(16x32) * V(32x64-window) ----
      union { f16x8 v; uint2 u2[2]; } pF;
      {
        const _Float16* pp = &Pbuf[wv][c * 36 + g * 8];
        pF.u2[0] = *(const uint2*)pp;
        pF.u2[1] = *(const uint2*)(pp + 4);
      }
#pragma unroll
      for (int jj = 0; jj < 4; ++jj)
#pragma unroll
        for (int r = 0; r < 4; ++r) accO[hi][jj][r] *= alr[r];
#pragma unroll
      for (int jj = 0; jj < 4; ++jj) {
        union { f16x8 v; uint2 u2[2]; } vF;
        const _Float16* vp = &Vsh[(16 * jj + c) * 132 + kb + g * 8];
        vF.u2[0] = *(const uint2*)vp;
        vF.u2[1] = *(const uint2*)(vp + 4);
        accO[hi][jj] = __builtin_amdgcn_mfma_f32_16x16x32_f16(pF.v, vF.v, accO[hi][jj], 0, 0, 0);
      }
    }
  }

  // ---- epilogue: redistribute s_run to q=4g+r rows, normalize, store ----
#pragma unroll
  for (int hi = 0; hi < 2; ++hi) {
    _Float16* ob = outh + ((size_t)b * NN + (h0 + hi) * Ww + w0) * Cc + head * HD;
#pragma unroll
    for (int r = 0; r < 4; ++r) {
      const float sr  = __shfl(s_run[hi], 4 * g + r, 16);
      const float inv = 1.f / sr;
      const int q = 4 * g + r;
#pragma unroll
      for (int jj = 0; jj < 4; ++jj)
        ob[(size_t)q * Cc + 16 * jj + c] = (_Float16)(accO[hi][jj][r] * inv);
    }
  }
}

// ---------------------------------------------------------------------------
extern "C" void kernel_launch(void* const* d_in, const int* in_sizes, int n_in,
                              void* d_out, int out_size, void* d_ws, size_t ws_size,
                              hipStream_t stream)
{
  const float* x      = (const float*)d_in[0];   // [32,1024,512]
  const float* w_qkv  = (const float*)d_in[1];   // [512,1536]
  const float* w_proj = (const float*)d_in[2];   // [512,512]
  const float* b_proj = (const float*)d_in[3];   // [512]
  float* out = (float*)d_out;

  const int M = Bsz * NN;                        // 32768
  char* ws = (char*)d_ws;
  _Float16* qkvh  = (_Float16*)ws;                              // 100.66 MB
  _Float16* attnh = (_Float16*)(ws + 100663296);                // 33.55 MB
  _Float16* wqT   = (_Float16*)(ws + 134217728);                // 1.57 MB
  _Float16* wpT   = (_Float16*)(ws + 134217728 + 1572864);      // 0.52 MB

  // weight transposes (f32 -> f16)
  tcvt<<<(ROWS * Cc + 255) / 256, 256, 0, stream>>>(w_qkv, wqT, ROWS, Cc);
  tcvt<<<(Cc * Cc + 255) / 256, 256, 0, stream>>>(w_proj, wpT, Cc, Cc);

  // qkv = x @ w_qkv   (fp32 A fused-converted in staging; f16 out)
  gemm_mfma<true, true, false><<<dim3(ROWS / 128, M / 128), 256, 0, stream>>>(
      x, wqT, nullptr, qkvh, ROWS, Cc);

  // local attention (MFMA, h-paired, swapped-QK softmax) -> f16 [32768,512]
  local_attn_mfma<<<dim3(Hh / 2, NHEAD, Bsz), 512, 0, stream>>>(qkvh, attnh);

  // out = attn @ w_proj + bias  (f32 out)
  gemm_mfma<false, false, true><<<dim3(Cc / 128, M / 128), 256, 0, stream>>>(
      attnh, wpT, b_proj, out, Cc, Cc);
}

// Round 10
// 194.382 us; speedup vs baseline: 1.1403x; 1.0960x over previous
//
#include <hip/hip_runtime.h>

#define Bsz   32
#define Hh    8
#define Ww    128
#define Cc    512
#define NHEAD 8
#define HD    64
#define NN    1024
#define SCALE 0.125f
#define ROWS  1536

typedef _Float16 f16x8 __attribute__((ext_vector_type(8)));
typedef float    f32x4 __attribute__((ext_vector_type(4)));

// ---------------------------------------------------------------------------
// async global->LDS, 16B per lane (linear dest = wave base + lane*16)
// ---------------------------------------------------------------------------
__device__ __forceinline__ void gload16(const _Float16* g, _Float16* l) {
#if __has_builtin(__builtin_amdgcn_global_load_lds)
  __builtin_amdgcn_global_load_lds(
      (const __attribute__((address_space(1))) unsigned int*)g,
      (__attribute__((address_space(3))) unsigned int*)l, 16, 0, 0);
#else
  *(uint4*)l = *(const uint4*)g;
#endif
}

// out[n*K + k] = in[k*Nn + n]  (f32 -> f16 transpose)
__global__ __launch_bounds__(256) void tcvt(
    const float* __restrict__ in, _Float16* __restrict__ out, int Nn, int K) {
  const int id = blockIdx.x * 256 + threadIdx.x;
  if (id < Nn * K) {
    const int n = id / K, k = id - n * K;
    out[id] = (_Float16)in[(size_t)k * Nn + n];
  }
}

// ---------------------------------------------------------------------------
// MFMA GEMM: C[M,Nn] = A[M,K] * BT[Nn,K]^T (f16 MFMA, +bias), 128x128 tile,
// BK=32, 4 waves, 4x4 fragments of mfma_f32_16x16x32_f16 per wave.
// A_F32: A is fp32 in global; staged via reg-convert + ds_write_b128 (fused
// x->f16 convert). 1D grid + XCD-chunked bijective swizzle (nwg%8==0):
// nid = (wg&7)*(nwg/8) + (wg>>3), bn = nid%nbx (fast) -> the nbx blocks
// sharing one A row-panel are contiguous within an XCD's chunk, so the
// panel is read once into that XCD's L2 (round 9: panel re-read x12 from
// HBM/L3, FETCH 273MB, gemm1 115us).
// ---------------------------------------------------------------------------
template<bool A_F32, bool OUT_F16, bool HAS_BIAS>
__global__ __launch_bounds__(256, 2) void gemm_mfma(
    const void* __restrict__ Ap,
    const _Float16* __restrict__ BT,
    const float* __restrict__ bias,
    void* __restrict__ Cout,
    int nbx, int Nn, int K)
{
  __shared__ _Float16 As[128 * 32];
  __shared__ _Float16 Bs[128 * 32];

  const int wg    = blockIdx.x;
  const int chunk = gridDim.x >> 3;
  const int nid   = (wg & 7) * chunk + (wg >> 3);
  const int bn    = (nid % nbx) * 128;
  const int bm    = (nid / nbx) * 128;

  const int t  = threadIdx.x;
  const int l  = t & 63, wv = t >> 6;
  const int wr = wv >> 1, wc = wv & 1;

  f32x4 acc[4][4] = {};

  const int arow = t >> 2;            // 0..63
  const int ac   = (t & 3) * 8;       // k chunk start (halfs)

  for (int k0 = 0; k0 < K; k0 += 32) {
    __syncthreads();
    if constexpr (A_F32) {
      const float* Af = (const float*)Ap;
#pragma unroll
      for (int rr = 0; rr < 2; ++rr) {
        const float* src = &Af[(size_t)(bm + arow + rr * 64) * K + k0 + ac];
        const float4 f0 = *(const float4*)src;
        const float4 f1 = *(const float4*)(src + 4);
        union { _Float16 h[8]; uint4 u; } pk;
        pk.h[0] = (_Float16)f0.x; pk.h[1] = (_Float16)f0.y;
        pk.h[2] = (_Float16)f0.z; pk.h[3] = (_Float16)f0.w;
        pk.h[4] = (_Float16)f1.x; pk.h[5] = (_Float16)f1.y;
        pk.h[6] = (_Float16)f1.z; pk.h[7] = (_Float16)f1.w;
        *(uint4*)&As[(arow + rr * 64) * 32 + ac] = pk.u;
      }
    } else {
      const _Float16* Ah = (const _Float16*)Ap;
      gload16(Ah + (size_t)(bm + arow)      * K + k0 + ac, &As[t * 8]);
      gload16(Ah + (size_t)(bm + 64 + arow) * K + k0 + ac, &As[2048 + t * 8]);
    }
    gload16(BT + (size_t)(bn + arow)      * K + k0 + ac, &Bs[t * 8]);
    gload16(BT + (size_t)(bn + 64 + arow) * K + k0 + ac, &Bs[2048 + t * 8]);
    __syncthreads();

    const int rA = l & 15, ks = (l >> 4) * 8;
    f16x8 aF[4], bF[4];
#pragma unroll
    for (int i = 0; i < 4; ++i)
      aF[i] = *(const f16x8*)&As[(wr * 64 + i * 16 + rA) * 32 + ks];
#pragma unroll
    for (int j = 0; j < 4; ++j)
      bF[j] = *(const f16x8*)&Bs[(wc * 64 + j * 16 + rA) * 32 + ks];
#pragma unroll
    for (int i = 0; i < 4; ++i)
#pragma unroll
      for (int j = 0; j < 4; ++j)
        acc[i][j] = __builtin_amdgcn_mfma_f32_16x16x32_f16(aF[i], bF[j], acc[i][j], 0, 0, 0);
  }

  const int lc = l & 15, lr4 = (l >> 4) * 4;
#pragma unroll
  for (int i = 0; i < 4; ++i) {
    const size_t row0 = (size_t)(bm + wr * 64 + i * 16 + lr4);
#pragma unroll
    for (int j = 0; j < 4; ++j) {
      const int col = bn + wc * 64 + j * 16 + lc;
      const float bv = HAS_BIAS ? bias[col] : 0.f;
#pragma unroll
      for (int r = 0; r < 4; ++r) {
        const float v = acc[i][j][r] + bv;
        if (OUT_F16)
          ((_Float16*)Cout)[(row0 + r) * Nn + col] = (_Float16)v;
        else
          ((float*)Cout)[(row0 + r) * Nn + col] = v;
      }
    }
  }
}

// ---------------------------------------------------------------------------
// MFMA local attention, h-paired + XCD-chunked + SWAPPED-QK softmax.
// QK^T computed as mfma(kF, qF) -- identical operand registers to the
// straight form, but output maps to S[kcol=kb+16tt+4g+r][q=w0+c]: each lane
// owns 8 scores of ONE query -> row softmax is 7 local fmax + 2 shfl (g-xor
// 16/32), 8 exps, + 4 shfl to redistribute alpha to PV's q=4g+r rows.
// Mask folded into an additive bias: s = fma(acc, SCALE, mbias).
// K read direct from global (L1/L2); V transposed into Vsh [d][132-pad];
// P via Pbuf [q*36+kcol] (2x uint2 stores/lane, ~2-way); PV mfma unchanged.
// ---------------------------------------------------------------------------
__global__ __launch_bounds__(512, 4) void local_attn_mfma(
    const _Float16* __restrict__ qkv, _Float16* __restrict__ outh)
{
  const int wg  = blockIdx.x + (Hh / 2) * (blockIdx.y + NHEAD * blockIdx.z);
  const int nid = ((wg & 7) << 7) + (wg >> 3);
  const int hp = nid & 3, head = (nid >> 2) & 7, b = nid >> 5;
  const int h0 = hp * 2;

  const int t = threadIdx.x;
  const int wv = t >> 6, l = t & 63;
  const int g = l >> 4, c = l & 15;
  const int w0 = wv * 16;                     // wave's query-col tile base
  const int kb = min(max(w0 - 8, 0), 96);     // 8-aligned key tile base

  __shared__ _Float16 Vsh[64 * 132];          // [d][132-pad cols]
  __shared__ _Float16 Pbuf[8][576];           // [wave][q*36 + kcol]

  const _Float16* qb = qkv + (size_t)b * NN * ROWS;

  // ---- Q fragments (lane c holds Q[w0+c][k-slice]; used as B-operand) ----
  f16x8 qF[2][2];
#pragma unroll
  for (int hi = 0; hi < 2; ++hi) {
    const _Float16* Qg = qb + (size_t)((h0 + hi) * Ww + w0 + c) * ROWS + head * HD;
    qF[hi][0] = *(const f16x8*)&Qg[g * 8];
    qF[hi][1] = *(const f16x8*)&Qg[32 + g * 8];
  }

  // ---- additive mask bias: kcol = kb+16tt+4g+r vs q = w0+c (h-indep) ----
  float mbias[2][4];
#pragma unroll
  for (int tt = 0; tt < 2; ++tt)
#pragma unroll
    for (int r = 0; r < 4; ++r) {
      const int kcol = kb + 16 * tt + 4 * g + r;
      const int qq   = w0 + c;
      mbias[tt][r] = (kcol >= qq - 5 && kcol <= qq + 5) ? 0.f : -1e30f;
    }

  const int r0 = max(0, h0 - 3), r1 = min(Hh - 1, h0 + 4);
  float m_run[2] = {-1e30f, -1e30f}, s_run[2] = {0.f, 0.f};
  f32x4 accO[2][4] = {};

  // V staging coords (threads t<256: 4 cols x 8 d each)
  const int dd = t & 7, cg = (t & 255) >> 3;

  for (int kr = r0; kr <= r1; ++kr) {
    __syncthreads();                          // prev PV reads of Vsh done
    if (t < 256) {
      f16x8 vr[4];
      const _Float16* Vg = qb + (size_t)(kr * Ww + cg * 4) * ROWS + 2 * Cc + head * HD + dd * 8;
#pragma unroll
      for (int i = 0; i < 4; ++i)
        vr[i] = *(const f16x8*)&Vg[(size_t)i * ROWS];
#pragma unroll
      for (int e = 0; e < 8; ++e) {
        union { _Float16 hh[4]; uint2 u; } pk;
        pk.hh[0] = vr[0][e]; pk.hh[1] = vr[1][e];
        pk.hh[2] = vr[2][e]; pk.hh[3] = vr[3][e];
        *(uint2*)&Vsh[(dd * 8 + e) * 132 + cg * 4] = pk.u;
      }
    }
    __syncthreads();                          // Vsh published

    const _Float16* Kg = qb + (size_t)(kr * Ww) * ROWS + Cc + head * HD;

#pragma unroll
    for (int hi = 0; hi < 2; ++hi) {
      const int hq = h0 + hi;
      if (kr < hq - 3 || kr > hq + 3) continue;

      // ---- swapped QK^T: Ssw[kcol_local=4g+r (+16tt)][q=c] ----
      f32x4 accS[2] = {};
#pragma unroll
      for (int tt = 0; tt < 2; ++tt) {
        const int col = kb + 16 * tt + c;
#pragma unroll
        for (int s = 0; s < 2; ++s) {
          const f16x8 kF = *(const f16x8*)&Kg[(size_t)col * ROWS + (s * 4 + g) * 8];
          accS[tt] = __builtin_amdgcn_mfma_f32_16x16x32_f16(kF, qF[hi][s], accS[tt], 0, 0, 0);
        }
      }

      // ---- lane-local softmax for query q = w0+c ----
      float sc[2][4];
      float smax = -1e30f;
#pragma unroll
      for (int tt = 0; tt < 2; ++tt)
#pragma unroll
        for (int r = 0; r < 4; ++r) {
          sc[tt][r] = __builtin_fmaf(accS[tt][r], SCALE, mbias[tt][r]);
          smax = fmaxf(smax, sc[tt][r]);
        }
      smax = fmaxf(smax, __shfl_xor(smax, 16));
      smax = fmaxf(smax, __shfl_xor(smax, 32));
      const float mnew  = fmaxf(m_run[hi], smax);
      const float alpha = __expf(m_run[hi] - mnew);
      m_run[hi] = mnew;

      float ps = 0.f;
#pragma unroll
      for (int tt = 0; tt < 2; ++tt) {
        float p0 = __expf(sc[tt][0] - mnew), p1 = __expf(sc[tt][1] - mnew);
        float p2 = __expf(sc[tt][2] - mnew), p3 = __expf(sc[tt][3] - mnew);
        ps += (p0 + p1) + (p2 + p3);
        union { _Float16 hh[4]; uint2 u; } pk;
        pk.hh[0] = (_Float16)p0; pk.hh[1] = (_Float16)p1;
        pk.hh[2] = (_Float16)p2; pk.hh[3] = (_Float16)p3;
        *(uint2*)&Pbuf[wv][c * 36 + 16 * tt + 4 * g] = pk.u;
      }
      ps += __shfl_xor(ps, 16);
      ps += __shfl_xor(ps, 32);
      s_run[hi] = s_run[hi] * alpha + ps;

      // redistribute alpha to this lane's accO rows (q = 4g+r)
      float alr[4];
#pragma unroll
      for (int r = 0; r < 4; ++r)
        alr[r] = __shfl(alpha, 4 * g + r, 16);

      // wave-local: drain P writes before re-reading as A-fragment
      asm volatile("s_waitcnt lgkmcnt(0)" ::: "memory");

      // ---- PV: O[q=4g+r][d=16jj+c] += P(16x32) * V(32x64-window) ----
      union { f16x8 v; uint2 u2[2]; } pF;
      {
        const _Float16* pp = &Pbuf[wv][c * 36 + g * 8];
        pF.u2[0] = *(const uint2*)pp;
        pF.u2[1] = *(const uint2*)(pp + 4);
      }
#pragma unroll
      for (int jj = 0; jj < 4; ++jj)
#pragma unroll
        for (int r = 0; r < 4; ++r) accO[hi][jj][r] *= alr[r];
#pragma unroll
      for (int jj = 0; jj < 4; ++jj) {
        union { f16x8 v; uint2 u2[2]; } vF;
        const _Float16* vp = &Vsh[(16 * jj + c) * 132 + kb + g * 8];
        vF.u2[0] = *(const uint2*)vp;
        vF.u2[1] = *(const uint2*)(vp + 4);
        accO[hi][jj] = __builtin_amdgcn_mfma_f32_16x16x32_f16(pF.v, vF.v, accO[hi][jj], 0, 0, 0);
      }
    }
  }

  // ---- epilogue: redistribute s_run to q=4g+r rows, normalize, store ----
#pragma unroll
  for (int hi = 0; hi < 2; ++hi) {
    _Float16* ob = outh + ((size_t)b * NN + (h0 + hi) * Ww + w0) * Cc + head * HD;
#pragma unroll
    for (int r = 0; r < 4; ++r) {
      const float sr  = __shfl(s_run[hi], 4 * g + r, 16);
      const float inv = 1.f / sr;
      const int q = 4 * g + r;
#pragma unroll
      for (int jj = 0; jj < 4; ++jj)
        ob[(size_t)q * Cc + 16 * jj + c] = (_Float16)(accO[hi][jj][r] * inv);
    }
  }
}

// ---------------------------------------------------------------------------
extern "C" void kernel_launch(void* const* d_in, const int* in_sizes, int n_in,
                              void* d_out, int out_size, void* d_ws, size_t ws_size,
                              hipStream_t stream)
{
  const float* x      = (const float*)d_in[0];   // [32,1024,512]
  const float* w_qkv  = (const float*)d_in[1];   // [512,1536]
  const float* w_proj = (const float*)d_in[2];   // [512,512]
  const float* b_proj = (const float*)d_in[3];   // [512]
  float* out = (float*)d_out;

  const int M = Bsz * NN;                        // 32768
  char* ws = (char*)d_ws;
  _Float16* qkvh  = (_Float16*)ws;                              // 100.66 MB
  _Float16* attnh = (_Float16*)(ws + 100663296);                // 33.55 MB
  _Float16* wqT   = (_Float16*)(ws + 134217728);                // 1.57 MB
  _Float16* wpT   = (_Float16*)(ws + 134217728 + 1572864);      // 0.52 MB

  // weight transposes (f32 -> f16)
  tcvt<<<(ROWS * Cc + 255) / 256, 256, 0, stream>>>(w_qkv, wqT, ROWS, Cc);
  tcvt<<<(Cc * Cc + 255) / 256, 256, 0, stream>>>(w_proj, wpT, Cc, Cc);

  // qkv = x @ w_qkv  (fp32 A fused-converted; f16 out; XCD-chunked grid)
  gemm_mfma<true, true, false><<<(ROWS / 128) * (M / 128), 256, 0, stream>>>(
      x, wqT, nullptr, qkvh, ROWS / 128, ROWS, Cc);

  // local attention (MFMA, h-paired, swapped-QK softmax) -> f16 [32768,512]
  local_attn_mfma<<<dim3(Hh / 2, NHEAD, Bsz), 512, 0, stream>>>(qkvh, attnh);

  // out = attn @ w_proj + bias  (f32 out; XCD-chunked grid)
  gemm_mfma<false, false, true><<<(Cc / 128) * (M / 128), 256, 0, stream>>>(
      attnh, wpT, b_proj, out, Cc / 128, Cc, Cc);
}

// Round 11
// 194.356 us; speedup vs baseline: 1.1404x; 1.0001x over previous
//
#include <hip/hip_runtime.h>

#define Bsz   32
#define Hh    8
#define Ww    128
#define Cc    512
#define NHEAD 8
#define HD    64
#define NN    1024
#define SCALE 0.125f
#define ROWS  1536

typedef _Float16 f16x8 __attribute__((ext_vector_type(8)));
typedef float    f32x4 __attribute__((ext_vector_type(4)));

// ---------------------------------------------------------------------------
// async global->LDS, 16B per lane (linear dest = wave base + lane*16)
// ---------------------------------------------------------------------------
__device__ __forceinline__ void gload16(const _Float16* g, _Float16* l) {
#if __has_builtin(__builtin_amdgcn_global_load_lds)
  __builtin_amdgcn_global_load_lds(
      (const __attribute__((address_space(1))) unsigned int*)g,
      (__attribute__((address_space(3))) unsigned int*)l, 16, 0, 0);
#else
  *(uint4*)l = *(const uint4*)g;
#endif
}

// out[n*K + k] = in[k*Nn + n]  (f32 -> f16 transpose)
__global__ __launch_bounds__(256) void tcvt(
    const float* __restrict__ in, _Float16* __restrict__ out, int Nn, int K) {
  const int id = blockIdx.x * 256 + threadIdx.x;
  if (id < Nn * K) {
    const int n = id / K, k = id - n * K;
    out[id] = (_Float16)in[(size_t)k * Nn + n];
  }
}

// ---------------------------------------------------------------------------
// MFMA GEMM, 2-phase double-buffered: C[M,Nn] = A[M,K] * BT[Nn,K]^T (+bias),
// 128x128 tile, BK=32, 4 waves, 4x4 fragments of mfma_f32_16x16x32_f16.
// Pipeline per K-step: issue A-loads(t+1)->regs + B gload_lds(t+1)->buf^1,
// compute(buf) [A-load latency hides under the 16 MFMAs], then cvt+ds_write
// A(t+1), syncthreads (vmcnt drain is cheap: B issued a compute-phase ago).
// Round 10 (single-buffered) had zero load/compute overlap: MfmaUtil 20%,
// VALU 17%, HBM 17% -- pure latency-bound.
// A_F32: A fp32 in global, fused convert in staging. 1D grid + XCD-chunked
// bijective swizzle (nid=(wg&7)*chunk+(wg>>3), bn fast) for L2 panel reuse.
// ---------------------------------------------------------------------------
template<bool A_F32, bool OUT_F16, bool HAS_BIAS>
__global__ __launch_bounds__(256, 2) void gemm_mfma(
    const void* __restrict__ Ap,
    const _Float16* __restrict__ BT,
    const float* __restrict__ bias,
    void* __restrict__ Cout,
    int nbx, int Nn, int K)
{
  __shared__ _Float16 As[2][128 * 32];
  __shared__ _Float16 Bs[2][128 * 32];

  const int wg    = blockIdx.x;
  const int chunk = gridDim.x >> 3;
  const int nid   = (wg & 7) * chunk + (wg >> 3);
  const int bn    = (nid % nbx) * 128;
  const int bm    = (nid / nbx) * 128;

  const int t  = threadIdx.x;
  const int l  = t & 63, wv = t >> 6;
  const int wr = wv >> 1, wc = wv & 1;

  f32x4 acc[4][4] = {};

  const int arow = t >> 2;            // 0..63
  const int ac   = (t & 3) * 8;       // k chunk start (halfs)

  // staged A regs (A_F32 path): 2 rows x 8 fp32
  float4 a0, a1, a2, a3;

  const float*    Af = (const float*)Ap;
  const _Float16* Ah = (const _Float16*)Ap;

  auto issueA = [&](int k0) {
    const float* s0 = &Af[(size_t)(bm + arow)      * K + k0 + ac];
    const float* s1 = &Af[(size_t)(bm + arow + 64) * K + k0 + ac];
    a0 = *(const float4*)s0; a1 = *(const float4*)(s0 + 4);
    a2 = *(const float4*)s1; a3 = *(const float4*)(s1 + 4);
  };
  auto writeA = [&](int pb) {
    union { _Float16 h[8]; uint4 u; } p0, p1;
    p0.h[0] = (_Float16)a0.x; p0.h[1] = (_Float16)a0.y;
    p0.h[2] = (_Float16)a0.z; p0.h[3] = (_Float16)a0.w;
    p0.h[4] = (_Float16)a1.x; p0.h[5] = (_Float16)a1.y;
    p0.h[6] = (_Float16)a1.z; p0.h[7] = (_Float16)a1.w;
    p1.h[0] = (_Float16)a2.x; p1.h[1] = (_Float16)a2.y;
    p1.h[2] = (_Float16)a2.z; p1.h[3] = (_Float16)a2.w;
    p1.h[4] = (_Float16)a3.x; p1.h[5] = (_Float16)a3.y;
    p1.h[6] = (_Float16)a3.z; p1.h[7] = (_Float16)a3.w;
    *(uint4*)&As[pb][arow * 32 + ac]        = p0.u;
    *(uint4*)&As[pb][(arow + 64) * 32 + ac] = p1.u;
  };
  auto gloadA = [&](int k0, int pb) {
    gload16(Ah + (size_t)(bm + arow)      * K + k0 + ac, &As[pb][t * 8]);
    gload16(Ah + (size_t)(bm + 64 + arow) * K + k0 + ac, &As[pb][2048 + t * 8]);
  };
  auto gloadB = [&](int k0, int pb) {
    gload16(BT + (size_t)(bn + arow)      * K + k0 + ac, &Bs[pb][t * 8]);
    gload16(BT + (size_t)(bn + 64 + arow) * K + k0 + ac, &Bs[pb][2048 + t * 8]);
  };

  const int nt = K / 32;

  // ---- prologue: stage tile 0 into buf 0 ----
  if constexpr (A_F32) { issueA(0); writeA(0); }
  else                 { gloadA(0, 0); }
  gloadB(0, 0);
  __syncthreads();

  int buf = 0;
  for (int tt = 0; tt < nt; ++tt) {
    const int k0n = (tt + 1) * 32;
    const bool more = (tt + 1 < nt);
    if (more) {
      if constexpr (A_F32) issueA(k0n);      // loads in flight under compute
      else                 gloadA(k0n, buf ^ 1);
      gloadB(k0n, buf ^ 1);
    }

    const int rA = l & 15, ks = (l >> 4) * 8;
    f16x8 aF[4], bF[4];
#pragma unroll
    for (int i = 0; i < 4; ++i)
      aF[i] = *(const f16x8*)&As[buf][(wr * 64 + i * 16 + rA) * 32 + ks];
#pragma unroll
    for (int j = 0; j < 4; ++j)
      bF[j] = *(const f16x8*)&Bs[buf][(wc * 64 + j * 16 + rA) * 32 + ks];
#pragma unroll
    for (int i = 0; i < 4; ++i)
#pragma unroll
      for (int j = 0; j < 4; ++j)
        acc[i][j] = __builtin_amdgcn_mfma_f32_16x16x32_f16(aF[i], bF[j], acc[i][j], 0, 0, 0);

    if (more) {
      if constexpr (A_F32) writeA(buf ^ 1);  // waits A regs (already landed)
    }
    __syncthreads();
    buf ^= 1;
  }

  const int lc = l & 15, lr4 = (l >> 4) * 4;
#pragma unroll
  for (int i = 0; i < 4; ++i) {
    const size_t row0 = (size_t)(bm + wr * 64 + i * 16 + lr4);
#pragma unroll
    for (int j = 0; j < 4; ++j) {
      const int col = bn + wc * 64 + j * 16 + lc;
      const float bv = HAS_BIAS ? bias[col] : 0.f;
#pragma unroll
      for (int r = 0; r < 4; ++r) {
        const float v = acc[i][j][r] + bv;
        if (OUT_F16)
          ((_Float16*)Cout)[(row0 + r) * Nn + col] = (_Float16)v;
        else
          ((float*)Cout)[(row0 + r) * Nn + col] = v;
      }
    }
  }
}

// ---------------------------------------------------------------------------
// MFMA local attention, h-paired + XCD-chunked + SWAPPED-QK softmax.
// QK^T computed as mfma(kF, qF) -- identical operand registers to the
// straight form, but output maps to S[kcol=kb+16tt+4g+r][q=w0+c]: each lane
// owns 8 scores of ONE query -> row softmax is 7 local fmax + 2 shfl (g-xor
// 16/32), 8 exps, + 4 shfl to redistribute alpha to PV's q=4g+r rows.
// Mask folded into an additive bias: s = fma(acc, SCALE, mbias).
// K read direct from global (L1/L2); V transposed into Vsh [d][132-pad];
// P via Pbuf [q*36+kcol] (2x uint2 stores/lane, ~2-way); PV mfma unchanged.
// ---------------------------------------------------------------------------
__global__ __launch_bounds__(512, 4) void local_attn_mfma(
    const _Float16* __restrict__ qkv, _Float16* __restrict__ outh)
{
  const int wg  = blockIdx.x + (Hh / 2) * (blockIdx.y + NHEAD * blockIdx.z);
  const int nid = ((wg & 7) << 7) + (wg >> 3);
  const int hp = nid & 3, head = (nid >> 2) & 7, b = nid >> 5;
  const int h0 = hp * 2;

  const int t = threadIdx.x;
  const int wv = t >> 6, l = t & 63;
  const int g = l >> 4, c = l & 15;
  const int w0 = wv * 16;                     // wave's query-col tile base
  const int kb = min(max(w0 - 8, 0), 96);     // 8-aligned key tile base

  __shared__ _Float16 Vsh[64 * 132];          // [d][132-pad cols]
  __shared__ _Float16 Pbuf[8][576];           // [wave][q*36 + kcol]

  const _Float16* qb = qkv + (size_t)b * NN * ROWS;

  // ---- Q fragments (lane c holds Q[w0+c][k-slice]; used as B-operand) ----
  f16x8 qF[2][2];
#pragma unroll
  for (int hi = 0; hi < 2; ++hi) {
    const _Float16* Qg = qb + (size_t)((h0 + hi) * Ww + w0 + c) * ROWS + head * HD;
    qF[hi][0] = *(const f16x8*)&Qg[g * 8];
    qF[hi][1] = *(const f16x8*)&Qg[32 + g * 8];
  }

  // ---- additive mask bias: kcol = kb+16tt+4g+r vs q = w0+c (h-indep) ----
  float mbias[2][4];
#pragma unroll
  for (int tt = 0; tt < 2; ++tt)
#pragma unroll
    for (int r = 0; r < 4; ++r) {
      const int kcol = kb + 16 * tt + 4 * g + r;
      const int qq   = w0 + c;
      mbias[tt][r] = (kcol >= qq - 5 && kcol <= qq + 5) ? 0.f : -1e30f;
    }

  const int r0 = max(0, h0 - 3), r1 = min(Hh - 1, h0 + 4);
  float m_run[2] = {-1e30f, -1e30f}, s_run[2] = {0.f, 0.f};
  f32x4 accO[2][4] = {};

  // V staging coords (threads t<256: 4 cols x 8 d each)
  const int dd = t & 7, cg = (t & 255) >> 3;

  for (int kr = r0; kr <= r1; ++kr) {
    __syncthreads();                          // prev PV reads of Vsh done
    if (t < 256) {
      f16x8 vr[4];
      const _Float16* Vg = qb + (size_t)(kr * Ww + cg * 4) * ROWS + 2 * Cc + head * HD + dd * 8;
#pragma unroll
      for (int i = 0; i < 4; ++i)
        vr[i] = *(const f16x8*)&Vg[(size_t)i * ROWS];
#pragma unroll
      for (int e = 0; e < 8; ++e) {
        union { _Float16 hh[4]; uint2 u; } pk;
        pk.hh[0] = vr[0][e]; pk.hh[1] = vr[1][e];
        pk.hh[2] = vr[2][e]; pk.hh[3] = vr[3][e];
        *(uint2*)&Vsh[(dd * 8 + e) * 132 + cg * 4] = pk.u;
      }
    }
    __syncthreads();                          // Vsh published

    const _Float16* Kg = qb + (size_t)(kr * Ww) * ROWS + Cc + head * HD;

#pragma unroll
    for (int hi = 0; hi < 2; ++hi) {
      const int hq = h0 + hi;
      if (kr < hq - 3 || kr > hq + 3) continue;

      // ---- swapped QK^T: Ssw[kcol_local=4g+r (+16tt)][q=c] ----
      f32x4 accS[2] = {};
#pragma unroll
      for (int tt = 0; tt < 2; ++tt) {
        const int col = kb + 16 * tt + c;
#pragma unroll
        for (int s = 0; s < 2; ++s) {
          const f16x8 kF = *(const f16x8*)&Kg[(size_t)col * ROWS + (s * 4 + g) * 8];
          accS[tt] = __builtin_amdgcn_mfma_f32_16x16x32_f16(kF, qF[hi][s], accS[tt], 0, 0, 0);
        }
      }

      // ---- lane-local softmax for query q = w0+c ----
      float sc[2][4];
      float smax = -1e30f;
#pragma unroll
      for (int tt = 0; tt < 2; ++tt)
#pragma unroll
        for (int r = 0; r < 4; ++r) {
          sc[tt][r] = __builtin_fmaf(accS[tt][r], SCALE, mbias[tt][r]);
          smax = fmaxf(smax, sc[tt][r]);
        }
      smax = fmaxf(smax, __shfl_xor(smax, 16));
      smax = fmaxf(smax, __shfl_xor(smax, 32));
      const float mnew  = fmaxf(m_run[hi], smax);
      const float alpha = __expf(m_run[hi] - mnew);
      m_run[hi] = mnew;

      float ps = 0.f;
#pragma unroll
      for (int tt = 0; tt < 2; ++tt) {
        float p0 = __expf(sc[tt][0] - mnew), p1 = __expf(sc[tt][1] - mnew);
        float p2 = __expf(sc[tt][2] - mnew), p3 = __expf(sc[tt][3] - mnew);
        ps += (p0 + p1) + (p2 + p3);
        union { _Float16 hh[4]; uint2 u; } pk;
        pk.hh[0] = (_Float16)p0; pk.hh[1] = (_Float16)p1;
        pk.hh[2] = (_Float16)p2; pk.hh[3] = (_Float16)p3;
        *(uint2*)&Pbuf[wv][c * 36 + 16 * tt + 4 * g] = pk.u;
      }
      ps += __shfl_xor(ps, 16);
      ps += __shfl_xor(ps, 32);
      s_run[hi] = s_run[hi] * alpha + ps;

      // redistribute alpha to this lane's accO rows (q = 4g+r)
      float alr[4];
#pragma unroll
      for (int r = 0; r < 4; ++r)
        alr[r] = __shfl(alpha, 4 * g + r, 16);

      // wave-local: drain P writes before re-reading as A-fragment
      asm volatile("s_waitcnt lgkmcnt(0)" ::: "memory");

      // ---- PV: O[q=4g+r][d=16jj+c] += P(16x32) * V(32x64-window) ----
      union { f16x8 v; uint2 u2[2]; } pF;
      {
        const _Float16* pp = &Pbuf[wv][c * 36 + g * 8];
        pF.u2[0] = *(const uint2*)pp;
        pF.u2[1] = *(const uint2*)(pp + 4);
      }
#pragma unroll
      for (int jj = 0; jj < 4; ++jj)
#pragma unroll
        for (int r = 0; r < 4; ++r) accO[hi][jj][r] *= alr[r];
#pragma unroll
      for (int jj = 0; jj < 4; ++jj) {
        union { f16x8 v; uint2 u2[2]; } vF;
        const _Float16* vp = &Vsh[(16 * jj + c) * 132 + kb + g * 8];
        vF.u2[0] = *(const uint2*)vp;
        vF.u2[1] = *(const uint2*)(vp + 4);
        accO[hi][jj] = __builtin_amdgcn_mfma_f32_16x16x32_f16(pF.v, vF.v, accO[hi][jj], 0, 0, 0);
      }
    }
  }

  // ---- epilogue: redistribute s_run to q=4g+r rows, normalize, store ----
#pragma unroll
  for (int hi = 0; hi < 2; ++hi) {
    _Float16* ob = outh + ((size_t)b * NN + (h0 + hi) * Ww + w0) * Cc + head * HD;
#pragma unroll
    for (int r = 0; r < 4; ++r) {
      const float sr  = __shfl(s_run[hi], 4 * g + r, 16);
      const float inv = 1.f / sr;
      const int q = 4 * g + r;
#pragma unroll
      for (int jj = 0; jj < 4; ++jj)
        ob[(size_t)q * Cc + 16 * jj + c] = (_Float16)(accO[hi][jj][r] * inv);
    }
  }
}

// ---------------------------------------------------------------------------
extern "C" void kernel_launch(void* const* d_in, const int* in_sizes, int n_in,
                              void* d_out, int out_size, void* d_ws, size_t ws_size,
                              hipStream_t stream)
{
  const float* x      = (const float*)d_in[0];   // [32,1024,512]
  const float* w_qkv  = (const float*)d_in[1];   // [512,1536]
  const float* w_proj = (const float*)d_in[2];   // [512,512]
  const float* b_proj = (const float*)d_in[3];   // [512]
  float* out = (float*)d_out;

  const int M = Bsz * NN;                        // 32768
  char* ws = (char*)d_ws;
  _Float16* qkvh  = (_Float16*)ws;                              // 100.66 MB
  _Float16* attnh = (_Float16*)(ws + 100663296);                // 33.55 MB
  _Float16* wqT   = (_Float16*)(ws + 134217728);                // 1.57 MB
  _Float16* wpT   = (_Float16*)(ws + 134217728 + 1572864);      // 0.52 MB

  // weight transposes (f32 -> f16)
  tcvt<<<(ROWS * Cc + 255) / 256, 256, 0, stream>>>(w_qkv, wqT, ROWS, Cc);
  tcvt<<<(Cc * Cc + 255) / 256, 256, 0, stream>>>(w_proj, wpT, Cc, Cc);

  // qkv = x @ w_qkv  (fp32 A fused-converted; f16 out; XCD-chunked grid)
  gemm_mfma<true, true, false><<<(ROWS / 128) * (M / 128), 256, 0, stream>>>(
      x, wqT, nullptr, qkvh, ROWS / 128, ROWS, Cc);

  // local attention (MFMA, h-paired, swapped-QK softmax) -> f16 [32768,512]
  local_attn_mfma<<<dim3(Hh / 2, NHEAD, Bsz), 512, 0, stream>>>(qkvh, attnh);

  // out = attn @ w_proj + bias  (f32 out; XCD-chunked grid)
  gemm_mfma<false, false, true><<<(Cc / 128) * (M / 128), 256, 0, stream>>>(
      attnh, wpT, b_proj, out, Cc / 128, Cc, Cc);
}